// Round 1
// baseline (784.031 us; speedup 1.0000x reference)
//
#include <hip/hip_runtime.h>
#include <hip/hip_bf16.h>
#include <math.h>

// Problem constants
#define S 768
#define E 512
#define H 8
#define DK 64
#define TOPK 384

// ---------------------------------------------------------------------------
// Generic fp32 GEMM with bias: C[M x N] = A[M x K] @ W[K x N] + b[N]
// Tile 64x64, BK=16, 256 threads, 4x4 per thread.
// ---------------------------------------------------------------------------
#define TILE_M 64
#define TILE_N 64
#define TILE_K 16

__global__ __launch_bounds__(256) void gemm_bias_kernel(
    const float* __restrict__ A, const float* __restrict__ W,
    const float* __restrict__ bias, float* __restrict__ C,
    int M, int N, int K) {
  __shared__ float As[TILE_K][TILE_M + 1];
  __shared__ float Ws[TILE_K][TILE_N + 1];
  const int tid = threadIdx.x;
  const int m0 = blockIdx.y * TILE_M;
  const int n0 = blockIdx.x * TILE_N;
  const int tm = (tid / 16) * 4;
  const int tn = (tid % 16) * 4;
  float acc[4][4] = {};
  for (int k0 = 0; k0 < K; k0 += TILE_K) {
    // load A tile (64 x 16)
    #pragma unroll
    for (int i = tid; i < TILE_M * TILE_K; i += 256) {
      int m = i / TILE_K, k = i % TILE_K;
      As[k][m] = A[(m0 + m) * K + (k0 + k)];
    }
    // load W tile (16 x 64)
    #pragma unroll
    for (int i = tid; i < TILE_K * TILE_N; i += 256) {
      int k = i / TILE_N, n = i % TILE_N;
      float v = 0.0f;
      if (n0 + n < N) v = W[(k0 + k) * N + (n0 + n)];
      Ws[k][n] = v;
    }
    __syncthreads();
    #pragma unroll
    for (int k = 0; k < TILE_K; ++k) {
      float a[4], w[4];
      #pragma unroll
      for (int j = 0; j < 4; ++j) a[j] = As[k][tm + j];
      #pragma unroll
      for (int j = 0; j < 4; ++j) w[j] = Ws[k][tn + j];
      #pragma unroll
      for (int x = 0; x < 4; ++x)
        #pragma unroll
        for (int y = 0; y < 4; ++y)
          acc[x][y] = fmaf(a[x], w[y], acc[x][y]);
    }
    __syncthreads();
  }
  #pragma unroll
  for (int x = 0; x < 4; ++x) {
    int m = m0 + tm + x;
    #pragma unroll
    for (int y = 0; y < 4; ++y) {
      int n = n0 + tn + y;
      if (n < N) C[m * N + n] = acc[x][y] + bias[n];
    }
  }
}

// ---------------------------------------------------------------------------
// Indexer: ISC[s][t] = sum_h relu( dot64(QI[s, h*64:], KI[t, :]) ) * WI[s][h]
// Block computes 32(s) x 32(t) tile; loops over 8 heads.
// ---------------------------------------------------------------------------
__global__ __launch_bounds__(256) void indexer_kernel(
    const float* __restrict__ QI,   // S x 512 (cols head-major)
    const float* __restrict__ KI,   // S x 64
    const float* __restrict__ WI,   // S x 8
    float* __restrict__ ISC) {      // S x S
  __shared__ float qs[32][65];
  __shared__ float ks[32][65];
  const int tid = threadIdx.x;
  const int s0 = blockIdx.y * 32;
  const int t0 = blockIdx.x * 32;
  const int sl = tid / 8;            // 0..31 (s within tile)
  const int tl0 = (tid % 8) * 4;     // start t within tile
  float acc[4] = {0.f, 0.f, 0.f, 0.f};
  for (int h = 0; h < H; ++h) {
    for (int i = tid; i < 32 * 64; i += 256) {
      int r = i / 64, d = i % 64;
      qs[r][d] = QI[(s0 + r) * E + h * DK + d];
      ks[r][d] = KI[(t0 + r) * DK + d];
    }
    __syncthreads();
    float w = WI[(s0 + sl) * H + h];
    float dot[4] = {0.f, 0.f, 0.f, 0.f};
    #pragma unroll 8
    for (int d = 0; d < 64; ++d) {
      float q = qs[sl][d];
      #pragma unroll
      for (int j = 0; j < 4; ++j)
        dot[j] = fmaf(q, ks[tl0 + j][d], dot[j]);
    }
    #pragma unroll
    for (int j = 0; j < 4; ++j)
      acc[j] += fmaxf(dot[j], 0.0f) * w;
    __syncthreads();
  }
  #pragma unroll
  for (int j = 0; j < 4; ++j)
    ISC[(s0 + sl) * S + (t0 + tl0 + j)] = acc[j];
}

// ---------------------------------------------------------------------------
// Top-k via bitonic sort of 1024 (value,index) pairs per row.
// Order: value descending, index ascending (matches jax.lax.top_k stability).
// Threads 0..383 then emit the selected indices.
// ---------------------------------------------------------------------------
__global__ __launch_bounds__(512) void topk_kernel(
    const float* __restrict__ ISC, int* __restrict__ TK) {
  __shared__ float v[1024];
  __shared__ int   ix[1024];
  const int s = blockIdx.x;
  const int tid = threadIdx.x;
  for (int i = tid; i < 1024; i += 512) {
    v[i] = (i < S) ? ISC[s * S + i] : -3.402823466e38f;
    ix[i] = i;
  }
  __syncthreads();
  for (int k = 2; k <= 1024; k <<= 1) {
    for (int j = k >> 1; j > 0; j >>= 1) {
      #pragma unroll
      for (int t = tid; t < 1024; t += 512) {
        int l = t ^ j;
        if (l > t) {
          float vt = v[t], vl = v[l];
          int it = ix[t], il = ix[l];
          // l_before_t: element at l should precede element at t in the
          // desired order (desc value, asc index)
          bool l_before_t = (vl > vt) || (vl == vt && il < it);
          bool up = ((t & k) == 0);
          if (up ? l_before_t : !l_before_t) {
            v[t] = vl; v[l] = vt;
            ix[t] = il; ix[l] = it;
          }
        }
      }
      __syncthreads();
    }
  }
  if (tid < TOPK) TK[s * TOPK + tid] = ix[tid];
}

// ---------------------------------------------------------------------------
// Sparse attention: one block per query token s; all 8 heads.
// ---------------------------------------------------------------------------
__global__ __launch_bounds__(256) void attn_kernel(
    const float* __restrict__ Q, const float* __restrict__ K,
    const float* __restrict__ V, const int* __restrict__ TK,
    float* __restrict__ ATT) {
  __shared__ float qs[E];
  __shared__ int   tk[TOPK];
  __shared__ float sc[H][TOPK];
  __shared__ float invh[H];
  const int s = blockIdx.x;
  const int tid = threadIdx.x;
  for (int i = tid; i < E; i += 256) qs[i] = Q[s * E + i];
  for (int i = tid; i < TOPK; i += 256) tk[i] = TK[s * TOPK + i];
  __syncthreads();
  const float scaling = 0.125f;  // 1/sqrt(64)
  // scores
  for (int i = tid; i < H * TOPK; i += 256) {
    int h = i / TOPK, kk = i % TOPK;
    int t = tk[kk];
    const float4* Kt = (const float4*)(K + t * E + h * DK);
    const float4* Qh = (const float4*)(qs + h * DK);
    float dot = 0.0f;
    #pragma unroll
    for (int d4 = 0; d4 < DK / 4; ++d4) {
      float4 kv = Kt[d4];
      float4 qv = Qh[d4];
      dot += kv.x * qv.x + kv.y * qv.y + kv.z * qv.z + kv.w * qv.w;
    }
    sc[h][kk] = dot * scaling;
  }
  __syncthreads();
  // per-head softmax (32 lanes per head)
  {
    int h = tid / 32, lane = tid % 32;
    float m = -3.402823466e38f;
    for (int kk = lane; kk < TOPK; kk += 32) m = fmaxf(m, sc[h][kk]);
    #pragma unroll
    for (int off = 16; off > 0; off >>= 1) m = fmaxf(m, __shfl_xor(m, off, 32));
    float ssum = 0.0f;
    for (int kk = lane; kk < TOPK; kk += 32) {
      float e = expf(sc[h][kk] - m);
      sc[h][kk] = e;
      ssum += e;
    }
    #pragma unroll
    for (int off = 16; off > 0; off >>= 1) ssum += __shfl_xor(ssum, off, 32);
    if (lane == 0) invh[h] = 1.0f / ssum;
  }
  __syncthreads();
  // weighted V accumulation
  for (int i = tid; i < E; i += 256) {
    int h = i / DK, d = i % DK;
    float acc = 0.0f;
    for (int kk = 0; kk < TOPK; ++kk) {
      acc = fmaf(sc[h][kk], V[tk[kk] * E + h * DK + d], acc);
    }
    ATT[s * E + i] = acc * invh[h];
  }
}

// ---------------------------------------------------------------------------
// Launch
// ---------------------------------------------------------------------------
extern "C" void kernel_launch(void* const* d_in, const int* in_sizes, int n_in,
                              void* d_out, int out_size, void* d_ws, size_t ws_size,
                              hipStream_t stream) {
  const float* x    = (const float*)d_in[0];
  const float* Wq   = (const float*)d_in[1];
  const float* bq   = (const float*)d_in[2];
  const float* Wk   = (const float*)d_in[3];
  const float* bk   = (const float*)d_in[4];
  const float* Wv   = (const float*)d_in[5];
  const float* bv   = (const float*)d_in[6];
  const float* Wo   = (const float*)d_in[7];
  const float* bo   = (const float*)d_in[8];
  const float* iqW  = (const float*)d_in[9];
  const float* iqb  = (const float*)d_in[10];
  const float* ikW  = (const float*)d_in[11];
  const float* ikb  = (const float*)d_in[12];
  const float* wpW  = (const float*)d_in[13];
  const float* wpb  = (const float*)d_in[14];

  float* ws = (float*)d_ws;
  float* Qb  = ws;                 // S*E
  float* Kb  = Qb + S * E;         // S*E
  float* Vb  = Kb + S * E;         // S*E
  float* QI  = Vb + S * E;         // S*E
  float* KI  = QI + S * E;         // S*DK
  float* WI  = KI + S * DK;        // S*H
  float* ISC = WI + S * H;         // S*S
  int*   TK  = (int*)(ISC + S * S);    // S*TOPK ints
  float* ATT = (float*)(TK + S * TOPK); // S*E

  dim3 blk(256);
  dim3 gFull(E / TILE_N, S / TILE_M);   // (8, 12)
  dim3 gKI(1, S / TILE_M);
  // projections
  gemm_bias_kernel<<<gFull, blk, 0, stream>>>(x, Wq, bq, Qb, S, E, E);
  gemm_bias_kernel<<<gFull, blk, 0, stream>>>(x, Wk, bk, Kb, S, E, E);
  gemm_bias_kernel<<<gFull, blk, 0, stream>>>(x, Wv, bv, Vb, S, E, E);
  gemm_bias_kernel<<<gFull, blk, 0, stream>>>(x, iqW, iqb, QI, S, E, E);
  gemm_bias_kernel<<<gKI, blk, 0, stream>>>(x, ikW, ikb, KI, S, DK, E);
  gemm_bias_kernel<<<gKI, blk, 0, stream>>>(x, wpW, wpb, WI, S, H, E);
  // indexer scores
  indexer_kernel<<<dim3(S / 32, S / 32), blk, 0, stream>>>(QI, KI, WI, ISC);
  // top-k per row
  topk_kernel<<<dim3(S), dim3(512), 0, stream>>>(ISC, TK);
  // sparse attention
  attn_kernel<<<dim3(S), blk, 0, stream>>>(Qb, Kb, Vb, TK, ATT);
  // output projection
  gemm_bias_kernel<<<gFull, blk, 0, stream>>>(ATT, Wo, bo, (float*)d_out, S, E, E);
}

// Round 2
// 328.821 us; speedup vs baseline: 2.3844x; 2.3844x over previous
//
#include <hip/hip_runtime.h>
#include <hip/hip_bf16.h>
#include <math.h>

// Problem constants
#define S 768
#define E 512
#define H 8
#define DK 64
#define TOPK 384

#define TM 64
#define TN 64
#define BK 16

// ---------------------------------------------------------------------------
// Shared 64x64 fp32 GEMM tile body (bias added), float4 LDS reads everywhere.
// C[m0:m0+64, n0:n0+64] = A[m0:, :K] @ W[:K, n0:] + bias   (W row-major K x N)
// 256 threads, 4x4 accumulators per thread.
// ---------------------------------------------------------------------------
__device__ __forceinline__ void gemm64_tile(
    const float* __restrict__ A, const float* __restrict__ W,
    const float* __restrict__ bias, float* __restrict__ C,
    int N, int K, int m0, int n0) {
  __shared__ __align__(16) float As[BK][72];   // [k][m], 72*4B=288B rows (16B-aligned)
  __shared__ __align__(16) float Ws[BK][68];   // [k][n], 272B rows
  const int tid = threadIdx.x;
  const int tm = (tid >> 4) << 2;     // 0..60
  const int tn = (tid & 15) << 2;     // 0..60
  const int am = tid >> 2;            // 0..63 (A row)
  const int ac = tid & 3;             // float4 index along k
  const int wr = tid >> 4;            // 0..15 (W k-row)
  const int wc = tid & 15;            // float4 index along n
  const bool fullN = (n0 + TN <= N);
  float acc[4][4] = {};
  for (int k0 = 0; k0 < K; k0 += BK) {
    // A tile 64m x 16k, store transposed As[k][m]
    float4 av = *(const float4*)(A + (m0 + am) * K + k0 + ac * 4);
    As[ac * 4 + 0][am] = av.x;
    As[ac * 4 + 1][am] = av.y;
    As[ac * 4 + 2][am] = av.z;
    As[ac * 4 + 3][am] = av.w;
    // W tile 16k x 64n
    if (fullN) {
      *(float4*)&Ws[wr][wc * 4] = *(const float4*)(W + (k0 + wr) * N + n0 + wc * 4);
    } else {
      #pragma unroll
      for (int j = 0; j < 4; ++j) {
        int n = n0 + wc * 4 + j;
        Ws[wr][wc * 4 + j] = (n < N) ? W[(k0 + wr) * N + n] : 0.0f;
      }
    }
    __syncthreads();
    #pragma unroll
    for (int k = 0; k < BK; ++k) {
      float4 a4 = *(const float4*)&As[k][tm];
      float4 w4 = *(const float4*)&Ws[k][tn];
      float ar[4] = {a4.x, a4.y, a4.z, a4.w};
      float wv[4] = {w4.x, w4.y, w4.z, w4.w};
      #pragma unroll
      for (int x = 0; x < 4; ++x)
        #pragma unroll
        for (int y = 0; y < 4; ++y)
          acc[x][y] = fmaf(ar[x], wv[y], acc[x][y]);
    }
    __syncthreads();
  }
  #pragma unroll
  for (int x = 0; x < 4; ++x) {
    int m = m0 + tm + x;
    #pragma unroll
    for (int y = 0; y < 4; ++y) {
      int n = n0 + tn + y;
      if (n < N) C[m * N + n] = acc[x][y] + bias[n];
    }
  }
}

// ---------------------------------------------------------------------------
// Fused projections: [Wq|Wk|Wv|iqW] (N=512 each, 8 tiles) + ikW (N=64, 1 tile)
// + wpW (N=8, 1 tile). blockIdx.x in [0,34), blockIdx.y in [0,12).
// ---------------------------------------------------------------------------
struct SegTable {
  const float* W[6];
  const float* b[6];
  float*       out[6];
};

__global__ __launch_bounds__(256) void fused_proj_kernel(
    const float* __restrict__ A, SegTable tab) {
  int bx = blockIdx.x;
  int seg, nt;
  if (bx < 32) { seg = bx >> 3; nt = bx & 7; }
  else         { seg = 4 + (bx - 32); nt = 0; }
  const int N = (seg < 4) ? 512 : (seg == 4 ? 64 : 8);
  gemm64_tile(A, tab.W[seg], tab.b[seg], tab.out[seg], N, E, blockIdx.y * TM, nt * TN);
}

__global__ __launch_bounds__(256) void gemm_bias64(
    const float* __restrict__ A, const float* __restrict__ W,
    const float* __restrict__ bias, float* __restrict__ C, int N, int K) {
  gemm64_tile(A, W, bias, C, N, K, blockIdx.y * TM, blockIdx.x * TN);
}

// ---------------------------------------------------------------------------
// Indexer: ISC[s][t] = sum_h relu( dot64(QI[s, h*64:], KI[t, :]) ) * WI[s][h]
// Tile 32(s) x 64(t), 256 threads, 2x4 per thread. K-tile staged once
// (head-invariant), d-major for float4 reads; Q-tile staged per head.
// ---------------------------------------------------------------------------
__global__ __launch_bounds__(256) void indexer_kernel(
    const float* __restrict__ QI,   // S x 512 (cols head-major)
    const float* __restrict__ KI,   // S x 64
    const float* __restrict__ WI,   // S x 8
    float* __restrict__ ISC) {      // S x S
  __shared__ __align__(16) float ks[DK][68];   // [d][t]
  __shared__ __align__(16) float qs[DK][36];   // [d][s]
  const int tid = threadIdx.x;
  const int s0 = blockIdx.y * 32;
  const int t0 = blockIdx.x * 64;
  // stage K tile: 64t x 64d
  {
    int t = tid >> 2;
    int cb = tid & 3;
    #pragma unroll
    for (int cc = 0; cc < 4; ++cc) {
      int c = cb + cc * 4;   // float4 index along d
      float4 kv = *(const float4*)(KI + (t0 + t) * DK + c * 4);
      ks[c * 4 + 0][t] = kv.x;
      ks[c * 4 + 1][t] = kv.y;
      ks[c * 4 + 2][t] = kv.z;
      ks[c * 4 + 3][t] = kv.w;
    }
  }
  const int si = (tid >> 4) * 2;   // 0..30
  const int ti = (tid & 15) * 4;   // 0..60
  float acc[2][4] = {};
  for (int h = 0; h < H; ++h) {
    __syncthreads();   // ks ready (h=0) / qs no longer read (h>0)
    #pragma unroll
    for (int r = 0; r < 2; ++r) {
      int idx = tid + r * 256;
      int s = idx >> 4;
      int c = idx & 15;
      float4 qv = *(const float4*)(QI + (s0 + s) * E + h * DK + c * 4);
      qs[c * 4 + 0][s] = qv.x;
      qs[c * 4 + 1][s] = qv.y;
      qs[c * 4 + 2][s] = qv.z;
      qs[c * 4 + 3][s] = qv.w;
    }
    __syncthreads();
    float dot[2][4] = {};
    #pragma unroll
    for (int d = 0; d < DK; ++d) {
      float4 kv = *(const float4*)&ks[d][ti];
      float kr[4] = {kv.x, kv.y, kv.z, kv.w};
      float q0 = qs[d][si];
      float q1 = qs[d][si + 1];
      #pragma unroll
      for (int j = 0; j < 4; ++j) {
        dot[0][j] = fmaf(q0, kr[j], dot[0][j]);
        dot[1][j] = fmaf(q1, kr[j], dot[1][j]);
      }
    }
    float w0 = WI[(s0 + si) * H + h];
    float w1 = WI[(s0 + si + 1) * H + h];
    #pragma unroll
    for (int j = 0; j < 4; ++j) {
      acc[0][j] += fmaxf(dot[0][j], 0.0f) * w0;
      acc[1][j] += fmaxf(dot[1][j], 0.0f) * w1;
    }
  }
  #pragma unroll
  for (int i = 0; i < 2; ++i) {
    float4 o = {acc[i][0], acc[i][1], acc[i][2], acc[i][3]};
    *(float4*)(ISC + (s0 + si + i) * S + t0 + ti) = o;
  }
}

// ---------------------------------------------------------------------------
// Top-k via bitonic sort of 1024 (value,index) pairs per row.
// Order: value descending, index ascending (matches jax.lax.top_k stability).
// ---------------------------------------------------------------------------
__global__ __launch_bounds__(512) void topk_kernel(
    const float* __restrict__ ISC, int* __restrict__ TK) {
  __shared__ float v[1024];
  __shared__ int   ix[1024];
  const int s = blockIdx.x;
  const int tid = threadIdx.x;
  for (int i = tid; i < 1024; i += 512) {
    v[i] = (i < S) ? ISC[s * S + i] : -3.402823466e38f;
    ix[i] = i;
  }
  __syncthreads();
  for (int k = 2; k <= 1024; k <<= 1) {
    for (int j = k >> 1; j > 0; j >>= 1) {
      #pragma unroll
      for (int t = tid; t < 1024; t += 512) {
        int l = t ^ j;
        if (l > t) {
          float vt = v[t], vl = v[l];
          int it = ix[t], il = ix[l];
          bool l_before_t = (vl > vt) || (vl == vt && il < it);
          bool up = ((t & k) == 0);
          if (up ? l_before_t : !l_before_t) {
            v[t] = vl; v[l] = vt;
            ix[t] = il; ix[l] = it;
          }
        }
      }
      __syncthreads();
    }
  }
  if (tid < TOPK) TK[s * TOPK + tid] = ix[tid];
}

// ---------------------------------------------------------------------------
// Sparse attention: one block per query token s; all 8 heads.
// ---------------------------------------------------------------------------
__global__ __launch_bounds__(256) void attn_kernel(
    const float* __restrict__ Q, const float* __restrict__ K,
    const float* __restrict__ V, const int* __restrict__ TK,
    float* __restrict__ ATT) {
  __shared__ float qs[E];
  __shared__ int   tk[TOPK];
  __shared__ float sc[H][TOPK];
  __shared__ float invh[H];
  const int s = blockIdx.x;
  const int tid = threadIdx.x;
  for (int i = tid; i < E; i += 256) qs[i] = Q[s * E + i];
  for (int i = tid; i < TOPK; i += 256) tk[i] = TK[s * TOPK + i];
  __syncthreads();
  const float scaling = 0.125f;  // 1/sqrt(64)
  for (int i = tid; i < H * TOPK; i += 256) {
    int h = i / TOPK, kk = i % TOPK;
    int t = tk[kk];
    const float4* Kt = (const float4*)(K + t * E + h * DK);
    const float4* Qh = (const float4*)(qs + h * DK);
    float dot = 0.0f;
    #pragma unroll
    for (int d4 = 0; d4 < DK / 4; ++d4) {
      float4 kv = Kt[d4];
      float4 qv = Qh[d4];
      dot += kv.x * qv.x + kv.y * qv.y + kv.z * qv.z + kv.w * qv.w;
    }
    sc[h][kk] = dot * scaling;
  }
  __syncthreads();
  {
    int h = tid / 32, lane = tid % 32;
    float m = -3.402823466e38f;
    for (int kk = lane; kk < TOPK; kk += 32) m = fmaxf(m, sc[h][kk]);
    #pragma unroll
    for (int off = 16; off > 0; off >>= 1) m = fmaxf(m, __shfl_xor(m, off, 32));
    float ssum = 0.0f;
    for (int kk = lane; kk < TOPK; kk += 32) {
      float e = expf(sc[h][kk] - m);
      sc[h][kk] = e;
      ssum += e;
    }
    #pragma unroll
    for (int off = 16; off > 0; off >>= 1) ssum += __shfl_xor(ssum, off, 32);
    if (lane == 0) invh[h] = 1.0f / ssum;
  }
  __syncthreads();
  for (int i = tid; i < E; i += 256) {
    int h = i / DK, d = i % DK;
    float acc = 0.0f;
    #pragma unroll 4
    for (int kk = 0; kk < TOPK; ++kk) {
      acc = fmaf(sc[h][kk], V[tk[kk] * E + h * DK + d], acc);
    }
    ATT[s * E + i] = acc * invh[h];
  }
}

// ---------------------------------------------------------------------------
// Launch
// ---------------------------------------------------------------------------
extern "C" void kernel_launch(void* const* d_in, const int* in_sizes, int n_in,
                              void* d_out, int out_size, void* d_ws, size_t ws_size,
                              hipStream_t stream) {
  const float* x    = (const float*)d_in[0];
  const float* Wq   = (const float*)d_in[1];
  const float* bq   = (const float*)d_in[2];
  const float* Wk   = (const float*)d_in[3];
  const float* bk   = (const float*)d_in[4];
  const float* Wv   = (const float*)d_in[5];
  const float* bv   = (const float*)d_in[6];
  const float* Wo   = (const float*)d_in[7];
  const float* bo   = (const float*)d_in[8];
  const float* iqW  = (const float*)d_in[9];
  const float* iqb  = (const float*)d_in[10];
  const float* ikW  = (const float*)d_in[11];
  const float* ikb  = (const float*)d_in[12];
  const float* wpW  = (const float*)d_in[13];
  const float* wpb  = (const float*)d_in[14];

  float* ws = (float*)d_ws;
  float* Qb  = ws;                 // S*E
  float* Kb  = Qb + S * E;         // S*E
  float* Vb  = Kb + S * E;         // S*E
  float* QI  = Vb + S * E;         // S*E
  float* KI  = QI + S * E;         // S*DK
  float* WI  = KI + S * DK;        // S*H
  float* ISC = WI + S * H;         // S*S
  int*   TK  = (int*)(ISC + S * S);     // S*TOPK ints
  float* ATT = (float*)(TK + S * TOPK); // S*E

  SegTable tab;
  tab.W[0] = Wq;  tab.b[0] = bq;  tab.out[0] = Qb;
  tab.W[1] = Wk;  tab.b[1] = bk;  tab.out[1] = Kb;
  tab.W[2] = Wv;  tab.b[2] = bv;  tab.out[2] = Vb;
  tab.W[3] = iqW; tab.b[3] = iqb; tab.out[3] = QI;
  tab.W[4] = ikW; tab.b[4] = ikb; tab.out[4] = KI;
  tab.W[5] = wpW; tab.b[5] = wpb; tab.out[5] = WI;

  // all 6 projections in one launch: 34 n-tiles x 12 m-tiles = 408 blocks
  fused_proj_kernel<<<dim3(34, S / TM), dim3(256), 0, stream>>>(x, tab);
  // indexer scores: 12 t-tiles x 24 s-tiles = 288 blocks
  indexer_kernel<<<dim3(S / 64, S / 32), dim3(256), 0, stream>>>(QI, KI, WI, ISC);
  // top-k per row
  topk_kernel<<<dim3(S), dim3(512), 0, stream>>>(ISC, TK);
  // sparse attention
  attn_kernel<<<dim3(S), dim3(256), 0, stream>>>(Qb, Kb, Vb, TK, ATT);
  // output projection
  gemm_bias64<<<dim3(E / TN, S / TM), dim3(256), 0, stream>>>(ATT, Wo, bo, (float*)d_out, E, E);
}